// Round 11
// baseline (717.368 us; speedup 1.0000x reference)
//
#include <hip/hip_runtime.h>

// WeightedGIN 2-layer + L2-normalize. N=50000, E=800000, D=64.
// dst-CSR built per call: hist + 2-stage scan + 2-phase binned reorder
// (bucket=dst>>8 matches scan blocks; phase B bucket-scatter has L2-coalescing
// sequential-cursor writes; phase C fine-scatters within 32KB L2-resident regions).
// Then atomic-free 16-lane-per-node gather, quad-per-node MLP.

#define DIM 64
#define SB 256    // scan block size == nodes per bucket
#define SPLIT 4   // blocks per bucket in fine_k

// ---- Pass 1: histogram of dst ----
__global__ __launch_bounds__(256) void hist_k(const int* __restrict__ ei,
                                              int* __restrict__ cnt, int n_edges) {
    int e = blockIdx.x * blockDim.x + threadIdx.x;
    if (e < n_edges) atomicAdd(&cnt[ei[n_edges + e]], 1);
}

// ---- Scan stage 1: per-block sums of cnt (== bucket edge counts) ----
__global__ __launch_bounds__(SB) void scan1_k(const int* __restrict__ cnt,
                                              int* __restrict__ bsum, int n) {
    __shared__ int red[SB];
    int i = blockIdx.x * SB + threadIdx.x;
    red[threadIdx.x] = (i < n) ? cnt[i] : 0;
    __syncthreads();
    for (int off = SB / 2; off > 0; off >>= 1) {
        if (threadIdx.x < off) red[threadIdx.x] += red[threadIdx.x + off];
        __syncthreads();
    }
    if (threadIdx.x == 0) bsum[blockIdx.x] = red[0];
}

// ---- Scan stage 2: rescans bsum + local scan -> offs, cursor, bucket base/cursor ----
__global__ __launch_bounds__(SB) void scan3_k(const int* __restrict__ cnt,
                                              const int* __restrict__ bsum,
                                              int* __restrict__ offs,
                                              int* __restrict__ cursor,
                                              int* __restrict__ bbase,
                                              int* __restrict__ bcur, int n, int nb) {
    __shared__ int sb[SB];
    __shared__ int sc[SB];
    int t = threadIdx.x;
    int bv = (t < nb) ? bsum[t] : 0;
    sb[t] = bv;
    __syncthreads();
    for (int off = 1; off < SB; off <<= 1) {
        int u = (t >= off) ? sb[t - off] : 0;
        __syncthreads();
        sb[t] += u;
        __syncthreads();
    }
    int block_off = (blockIdx.x == 0) ? 0 : sb[blockIdx.x - 1];
    if (t == 0) { bbase[blockIdx.x] = block_off; bcur[blockIdx.x] = block_off; }
    __syncthreads();
    int i = blockIdx.x * SB + t;
    int v = (i < n) ? cnt[i] : 0;
    sc[t] = v;
    __syncthreads();
    for (int off = 1; off < SB; off <<= 1) {
        int u = (t >= off) ? sc[t - off] : 0;
        __syncthreads();
        sc[t] += u;
        __syncthreads();
    }
    int excl = sc[t] - v + block_off;
    if (i < n) { offs[i] = excl; cursor[i] = excl; }
    if (i == n - 1) offs[n] = excl + v;
}

// ---- Phase B: bucket-scatter. Sequential bucket cursors -> L2-coalesced writes. ----
// Payload packs src (bits 0-15), dst&255 (bits 16-23) in .x; weight in .y.
__global__ __launch_bounds__(256) void binscatter_k(const int* __restrict__ ei,
                                                    const float* __restrict__ ew,
                                                    int* __restrict__ bcur,
                                                    float2* __restrict__ bsw, int n_edges) {
    int e = blockIdx.x * blockDim.x + threadIdx.x;
    if (e >= n_edges) return;
    int s = ei[e];
    int d = ei[n_edges + e];
    int b = d >> 8;
    int pos = atomicAdd(&bcur[b], 1);
    unsigned u = (unsigned)s | ((unsigned)(d & 255) << 16);
    bsw[pos] = make_float2(__uint_as_float(u), ew[e]);
}

// ---- Phase C: fine scatter within each bucket (32KB L2-resident region). ----
__global__ __launch_bounds__(256) void fine_k(const float2* __restrict__ bsw,
                                              const int* __restrict__ bbase,
                                              int* __restrict__ cursor,
                                              float2* __restrict__ se,
                                              int n_edges, int nb) {
    int b = blockIdx.x / SPLIT;
    int q = blockIdx.x - b * SPLIT;
    int start = bbase[b];
    int end = (b + 1 < nb) ? bbase[b + 1] : n_edges;
    int len = end - start;
    int qs = start + (int)(((long long)len * q) / SPLIT);
    int qe = start + (int)(((long long)len * (q + 1)) / SPLIT);
    for (int i = qs + (int)threadIdx.x; i < qe; i += 256) {
        float2 pw = bsw[i];
        unsigned u = __float_as_uint(pw.x);
        int node = (b << 8) + (int)(u >> 16);
        int pos = atomicAdd(&cursor[node], 1);
        se[pos] = make_float2(__uint_as_float(u & 0xFFFFu), pw.y);
    }
}

// ---- Per layer: 16-lane-per-node gather (atomic-free) ----
__global__ __launch_bounds__(256) void gather_k(const float4* __restrict__ x4,
                                                const float4* __restrict__ se4,
                                                const int* __restrict__ offs,
                                                float4* __restrict__ agg4, int n_nodes) {
    int t = blockIdx.x * blockDim.x + threadIdx.x;
    int node = t >> 4;
    int li = t & 15;
    if (node >= n_nodes) return;
    int beg = offs[node], end = offs[node + 1];
    const float2* se2 = reinterpret_cast<const float2*>(se4);

    float4 a0 = make_float4(0.f, 0.f, 0.f, 0.f);
    float4 a1 = make_float4(0.f, 0.f, 0.f, 0.f);
    float4 a2 = make_float4(0.f, 0.f, 0.f, 0.f);
    float4 a3 = make_float4(0.f, 0.f, 0.f, 0.f);

    int e = beg;
    if ((e & 1) && e < end) {
        float2 p = se2[e];
        float4 v = x4[(size_t)__float_as_int(p.x) * 16 + li];
        a0.x = fmaf(p.y, v.x, a0.x); a0.y = fmaf(p.y, v.y, a0.y);
        a0.z = fmaf(p.y, v.z, a0.z); a0.w = fmaf(p.y, v.w, a0.w);
        ++e;
    }
    for (; e + 3 < end; e += 4) {
        float4 qa = se4[e >> 1];
        float4 qb = se4[(e >> 1) + 1];
        float4 v0 = x4[(size_t)__float_as_int(qa.x) * 16 + li];
        float4 v1 = x4[(size_t)__float_as_int(qa.z) * 16 + li];
        float4 v2 = x4[(size_t)__float_as_int(qb.x) * 16 + li];
        float4 v3 = x4[(size_t)__float_as_int(qb.z) * 16 + li];
        a0.x = fmaf(qa.y, v0.x, a0.x); a0.y = fmaf(qa.y, v0.y, a0.y);
        a0.z = fmaf(qa.y, v0.z, a0.z); a0.w = fmaf(qa.y, v0.w, a0.w);
        a1.x = fmaf(qa.w, v1.x, a1.x); a1.y = fmaf(qa.w, v1.y, a1.y);
        a1.z = fmaf(qa.w, v1.z, a1.z); a1.w = fmaf(qa.w, v1.w, a1.w);
        a2.x = fmaf(qb.y, v2.x, a2.x); a2.y = fmaf(qb.y, v2.y, a2.y);
        a2.z = fmaf(qb.y, v2.z, a2.z); a2.w = fmaf(qb.y, v2.w, a2.w);
        a3.x = fmaf(qb.w, v3.x, a3.x); a3.y = fmaf(qb.w, v3.y, a3.y);
        a3.z = fmaf(qb.w, v3.z, a3.z); a3.w = fmaf(qb.w, v3.w, a3.w);
    }
    if (e + 1 < end) {
        float4 qa = se4[e >> 1];
        float4 v0 = x4[(size_t)__float_as_int(qa.x) * 16 + li];
        float4 v1 = x4[(size_t)__float_as_int(qa.z) * 16 + li];
        a0.x = fmaf(qa.y, v0.x, a0.x); a0.y = fmaf(qa.y, v0.y, a0.y);
        a0.z = fmaf(qa.y, v0.z, a0.z); a0.w = fmaf(qa.y, v0.w, a0.w);
        a1.x = fmaf(qa.w, v1.x, a1.x); a1.y = fmaf(qa.w, v1.y, a1.y);
        a1.z = fmaf(qa.w, v1.z, a1.z); a1.w = fmaf(qa.w, v1.w, a1.w);
        e += 2;
    }
    if (e < end) {
        float2 p = se2[e];
        float4 v = x4[(size_t)__float_as_int(p.x) * 16 + li];
        a0.x = fmaf(p.y, v.x, a0.x); a0.y = fmaf(p.y, v.y, a0.y);
        a0.z = fmaf(p.y, v.z, a0.z); a0.w = fmaf(p.y, v.w, a0.w);
    }
    float4 r;
    r.x = (a0.x + a1.x) + (a2.x + a3.x);
    r.y = (a0.y + a1.y) + (a2.y + a3.y);
    r.z = (a0.z + a1.z) + (a2.z + a3.z);
    r.w = (a0.w + a1.w) + (a2.w + a3.w);
    agg4[(size_t)node * 16 + li] = r;
}

// ---- MLP: quad-per-node, stride-4 j interleave, stride-17 padded LDS ----
#define WPAD 17
__device__ __forceinline__ float4 shfl_xor4(float4 v, int m) {
    v.x = __shfl_xor(v.x, m, 64);
    v.y = __shfl_xor(v.y, m, 64);
    v.z = __shfl_xor(v.z, m, 64);
    v.w = __shfl_xor(v.w, m, 64);
    return v;
}

__global__ __launch_bounds__(256) void mlp_k(const float4* __restrict__ agg4,
                                             const float* __restrict__ W1,
                                             const float* __restrict__ W2,
                                             float4* __restrict__ out4,
                                             int n_nodes, int do_norm) {
    __shared__ float4 sW1[DIM * WPAD];    // [j][k4], stride-17 pad
    __shared__ float4 sW2T[DIM * WPAD];   // [j][j2_4] = W2[j2][j] transposed, padded
    for (int i = threadIdx.x; i < DIM * (DIM / 4); i += blockDim.x) {
        int j = i >> 4, k4 = i & 15;
        sW1[j * WPAD + k4] = reinterpret_cast<const float4*>(W1)[i];
    }
    for (int i = threadIdx.x; i < DIM * DIM; i += blockDim.x) {
        int j2 = i >> 6, j = i & 63;   // W2[j2][j]
        reinterpret_cast<float*>(sW2T)[(j * WPAD + (j2 >> 2)) * 4 + (j2 & 3)] = W2[i];
    }
    __syncthreads();

    int t = blockIdx.x * blockDim.x + threadIdx.x;
    int node = t >> 2;
    int q = t & 3;
    if (node >= n_nodes) return;

    float4 a[DIM / 4];
#pragma unroll
    for (int k4 = 0; k4 < DIM / 4; ++k4)
        a[k4] = agg4[(size_t)node * 16 + k4];

    float4 o[DIM / 4];
#pragma unroll
    for (int j4 = 0; j4 < DIM / 4; ++j4) o[j4] = make_float4(0.f, 0.f, 0.f, 0.f);

    for (int jj = 0; jj < 16; ++jj) {
        int j = q + (jj << 2);          // stride-4 interleave across the quad
        float h = 0.f;
#pragma unroll
        for (int k4 = 0; k4 < 16; ++k4) {
            float4 wv = sW1[j * WPAD + k4];
            h = fmaf(a[k4].x, wv.x, h);
            h = fmaf(a[k4].y, wv.y, h);
            h = fmaf(a[k4].z, wv.z, h);
            h = fmaf(a[k4].w, wv.w, h);
        }
        h = fmaxf(h, 0.f);
#pragma unroll
        for (int j4 = 0; j4 < 16; ++j4) {
            float4 wv = sW2T[j * WPAD + j4];
            o[j4].x = fmaf(h, wv.x, o[j4].x);
            o[j4].y = fmaf(h, wv.y, o[j4].y);
            o[j4].z = fmaf(h, wv.z, o[j4].z);
            o[j4].w = fmaf(h, wv.w, o[j4].w);
        }
    }

#pragma unroll
    for (int j4 = 0; j4 < 16; ++j4) {
        float4 p = shfl_xor4(o[j4], 1);
        o[j4].x += p.x; o[j4].y += p.y; o[j4].z += p.z; o[j4].w += p.w;
        p = shfl_xor4(o[j4], 2);
        o[j4].x += p.x; o[j4].y += p.y; o[j4].z += p.z; o[j4].w += p.w;
    }

    if (q != 0) return;   // lane 0 of quad holds the full row now

    float scale = 1.f;
    if (do_norm) {
        float ss = 0.f;
#pragma unroll
        for (int j4 = 0; j4 < 16; ++j4) {
            ss = fmaf(o[j4].x, o[j4].x, ss);
            ss = fmaf(o[j4].y, o[j4].y, ss);
            ss = fmaf(o[j4].z, o[j4].z, ss);
            ss = fmaf(o[j4].w, o[j4].w, ss);
        }
        scale = 1.f / fmaxf(sqrtf(ss), 1e-12f);
    }

#pragma unroll
    for (int j4 = 0; j4 < 16; ++j4) {
        float4 v = o[j4];
        v.x *= scale; v.y *= scale; v.z *= scale; v.w *= scale;
        out4[(size_t)node * 16 + j4] = v;
    }
}

extern "C" void kernel_launch(void* const* d_in, const int* in_sizes, int n_in,
                              void* d_out, int out_size, void* d_ws, size_t ws_size,
                              hipStream_t stream) {
    const float* x    = (const float*)d_in[0];
    const int*   ei   = (const int*)d_in[1];     // [2,E]: src row then dst row
    const float* ew   = (const float*)d_in[2];
    const float* W1_0 = (const float*)d_in[3];
    const float* W2_0 = (const float*)d_in[4];
    const float* W1_1 = (const float*)d_in[5];
    const float* W2_1 = (const float*)d_in[6];
    float* out = (float*)d_out;

    int n_nodes = in_sizes[0] / DIM;
    int n_edges = in_sizes[2];

    char* p = (char*)d_ws;
    auto carve = [&](size_t bytes) {
        char* r = p;
        p += (bytes + 15) & ~(size_t)15;
        return r;
    };
    int nb = (n_nodes + SB - 1) / SB;                // 196 buckets (<=256)
    int*    cnt    = (int*)carve((size_t)n_nodes * sizeof(int));
    int*    offs   = (int*)carve(((size_t)n_nodes + 1) * sizeof(int));
    int*    cursor = (int*)carve((size_t)n_nodes * sizeof(int));
    int*    bsum   = (int*)carve((size_t)nb * sizeof(int));
    int*    bbase  = (int*)carve((size_t)nb * sizeof(int));
    int*    bcur   = (int*)carve((size_t)nb * sizeof(int));
    float2* se     = (float2*)carve((size_t)n_edges * sizeof(float2));
    float*  agg    = (float*)carve((size_t)n_nodes * DIM * sizeof(float));
    float2* bsw    = (float2*)agg;   // overlap: bsw dead before gather writes agg

    int eb  = (n_edges + 255) / 256;
    int gb  = (n_nodes * 16 + 255) / 256;    // 16 lanes per node (gather)
    int mb4 = (n_nodes * 4 + 255) / 256;     // 4 threads per node (mlp)

    // ---- build dst-CSR (shared by both layers) ----
    hipMemsetAsync(cnt, 0, (size_t)n_nodes * sizeof(int), stream);
    hist_k<<<eb, 256, 0, stream>>>(ei, cnt, n_edges);
    scan1_k<<<nb, SB, 0, stream>>>(cnt, bsum, n_nodes);
    scan3_k<<<nb, SB, 0, stream>>>(cnt, bsum, offs, cursor, bbase, bcur, n_nodes, nb);
    binscatter_k<<<eb, 256, 0, stream>>>(ei, ew, bcur, bsw, n_edges);
    fine_k<<<nb * SPLIT, 256, 0, stream>>>(bsw, bbase, cursor, se, n_edges, nb);

    // ---- layer 1 ----
    gather_k<<<gb, 256, 0, stream>>>((const float4*)x, (const float4*)se, offs,
                                     (float4*)agg, n_nodes);
    mlp_k<<<mb4, 256, 0, stream>>>((const float4*)agg, W1_0, W2_0,
                                   (float4*)out, n_nodes, 0);

    // ---- layer 2 (x1 lives in d_out) ----
    gather_k<<<gb, 256, 0, stream>>>((const float4*)out, (const float4*)se, offs,
                                     (float4*)agg, n_nodes);
    mlp_k<<<mb4, 256, 0, stream>>>((const float4*)agg, W1_1, W2_1,
                                   (float4*)out, n_nodes, 1);
}

// Round 13
// 326.103 us; speedup vs baseline: 2.1998x; 2.1998x over previous
//
#include <hip/hip_runtime.h>
#include <hip/hip_fp16.h>

// WeightedGIN 2-layer + L2-normalize. N=50000, E=800000, D=64.
// R7 pipeline (binned 2-phase reorder abandoned: 196-counter returning atomics
// serialize ~110ns/op -> 450us). Changes vs R7:
//  - se packed to 4B (src:16 | f16 w:16): se = 3.2MB < 4MiB/XCD L2 -> scatter
//    lines stay resident, writeback ~payload instead of 52MB amplified.
//  - mlp h-accumulation split 4-way + jj unroll 2 (was a 64-deep dependent
//    fma chain; VALUBusy 16% at 3 waves/SIMD).

#define DIM 64
#define SB 256   // scan block size

// ---- Pass 1: histogram of dst ----
__global__ __launch_bounds__(256) void hist_k(const int* __restrict__ ei,
                                              int* __restrict__ cnt, int n_edges) {
    int e = blockIdx.x * blockDim.x + threadIdx.x;
    if (e < n_edges) atomicAdd(&cnt[ei[n_edges + e]], 1);
}

// ---- Scan stage 1: per-block sums of cnt ----
__global__ __launch_bounds__(SB) void scan1_k(const int* __restrict__ cnt,
                                              int* __restrict__ bsum, int n) {
    __shared__ int red[SB];
    int i = blockIdx.x * SB + threadIdx.x;
    red[threadIdx.x] = (i < n) ? cnt[i] : 0;
    __syncthreads();
    for (int off = SB / 2; off > 0; off >>= 1) {
        if (threadIdx.x < off) red[threadIdx.x] += red[threadIdx.x + off];
        __syncthreads();
    }
    if (threadIdx.x == 0) bsum[blockIdx.x] = red[0];
}

// ---- Scan stage 2: each block re-scans bsum (nb<=256) + local scan -> offs, cursor ----
__global__ __launch_bounds__(SB) void scan3_k(const int* __restrict__ cnt,
                                              const int* __restrict__ bsum,
                                              int* __restrict__ offs,
                                              int* __restrict__ cursor, int n, int nb) {
    __shared__ int sb[SB];
    __shared__ int sc[SB];
    int t = threadIdx.x;
    int bv = (t < nb) ? bsum[t] : 0;
    sb[t] = bv;
    __syncthreads();
    for (int off = 1; off < SB; off <<= 1) {
        int u = (t >= off) ? sb[t - off] : 0;
        __syncthreads();
        sb[t] += u;
        __syncthreads();
    }
    int block_off = (blockIdx.x == 0) ? 0 : sb[blockIdx.x - 1];
    __syncthreads();
    int i = blockIdx.x * SB + t;
    int v = (i < n) ? cnt[i] : 0;
    sc[t] = v;
    __syncthreads();
    for (int off = 1; off < SB; off <<= 1) {
        int u = (t >= off) ? sc[t - off] : 0;
        __syncthreads();
        sc[t] += u;
        __syncthreads();
    }
    int excl = sc[t] - v + block_off;
    if (i < n) { offs[i] = excl; cursor[i] = excl; }
    if (i == n - 1) offs[n] = excl + v;
}

// ---- Pass 3: scatter edges into dst-sorted packed payload (src | f16 w << 16) ----
__global__ __launch_bounds__(256) void reorder_k(const int* __restrict__ ei,
                                                 const float* __restrict__ ew,
                                                 int* __restrict__ cursor,
                                                 unsigned* __restrict__ se, int n_edges) {
    int e = blockIdx.x * blockDim.x + threadIdx.x;
    if (e >= n_edges) return;
    int s = ei[e];
    int d = ei[n_edges + e];
    unsigned hw = (unsigned)__half_as_ushort(__float2half_rn(ew[e]));
    int pos = atomicAdd(&cursor[d], 1);
    se[pos] = (unsigned)s | (hw << 16);
}

// ---- Per layer: 16-lane-per-node gather (atomic-free) ----
// Group of 16 lanes owns one node; lane li holds float4 chunk li of the row.
__global__ __launch_bounds__(256) void gather_k(const float4* __restrict__ x4,
                                                const unsigned* __restrict__ se,
                                                const int* __restrict__ offs,
                                                float4* __restrict__ agg4, int n_nodes) {
    int t = blockIdx.x * blockDim.x + threadIdx.x;
    int node = t >> 4;
    int li = t & 15;
    if (node >= n_nodes) return;
    int beg = offs[node], end = offs[node + 1];

    float4 a0 = make_float4(0.f, 0.f, 0.f, 0.f);
    float4 a1 = make_float4(0.f, 0.f, 0.f, 0.f);
    float4 a2 = make_float4(0.f, 0.f, 0.f, 0.f);
    float4 a3 = make_float4(0.f, 0.f, 0.f, 0.f);

    int e = beg;
    for (; e + 3 < end; e += 4) {          // 4 edges in flight (payload seq 4B loads)
        unsigned u0 = se[e], u1 = se[e + 1], u2 = se[e + 2], u3 = se[e + 3];
        float w0 = __half2float(__ushort_as_half((unsigned short)(u0 >> 16)));
        float w1 = __half2float(__ushort_as_half((unsigned short)(u1 >> 16)));
        float w2 = __half2float(__ushort_as_half((unsigned short)(u2 >> 16)));
        float w3 = __half2float(__ushort_as_half((unsigned short)(u3 >> 16)));
        float4 v0 = x4[(size_t)(u0 & 0xFFFFu) * 16 + li];
        float4 v1 = x4[(size_t)(u1 & 0xFFFFu) * 16 + li];
        float4 v2 = x4[(size_t)(u2 & 0xFFFFu) * 16 + li];
        float4 v3 = x4[(size_t)(u3 & 0xFFFFu) * 16 + li];
        a0.x = fmaf(w0, v0.x, a0.x); a0.y = fmaf(w0, v0.y, a0.y);
        a0.z = fmaf(w0, v0.z, a0.z); a0.w = fmaf(w0, v0.w, a0.w);
        a1.x = fmaf(w1, v1.x, a1.x); a1.y = fmaf(w1, v1.y, a1.y);
        a1.z = fmaf(w1, v1.z, a1.z); a1.w = fmaf(w1, v1.w, a1.w);
        a2.x = fmaf(w2, v2.x, a2.x); a2.y = fmaf(w2, v2.y, a2.y);
        a2.z = fmaf(w2, v2.z, a2.z); a2.w = fmaf(w2, v2.w, a2.w);
        a3.x = fmaf(w3, v3.x, a3.x); a3.y = fmaf(w3, v3.y, a3.y);
        a3.z = fmaf(w3, v3.z, a3.z); a3.w = fmaf(w3, v3.w, a3.w);
    }
    for (; e < end; ++e) {
        unsigned u = se[e];
        float w = __half2float(__ushort_as_half((unsigned short)(u >> 16)));
        float4 v = x4[(size_t)(u & 0xFFFFu) * 16 + li];
        a0.x = fmaf(w, v.x, a0.x); a0.y = fmaf(w, v.y, a0.y);
        a0.z = fmaf(w, v.z, a0.z); a0.w = fmaf(w, v.w, a0.w);
    }
    float4 r;
    r.x = (a0.x + a1.x) + (a2.x + a3.x);
    r.y = (a0.y + a1.y) + (a2.y + a3.y);
    r.z = (a0.z + a1.z) + (a2.z + a3.z);
    r.w = (a0.w + a1.w) + (a2.w + a3.w);
    agg4[(size_t)node * 16 + li] = r;
}

// ---- MLP: quad-per-node, stride-4 j interleave, stride-17 padded LDS ----
// h accumulation split into 4 parallel partials (was 64-deep dependent chain);
// jj unrolled 2x for cross-iteration ILP.
#define WPAD 17
__device__ __forceinline__ float4 shfl_xor4(float4 v, int m) {
    v.x = __shfl_xor(v.x, m, 64);
    v.y = __shfl_xor(v.y, m, 64);
    v.z = __shfl_xor(v.z, m, 64);
    v.w = __shfl_xor(v.w, m, 64);
    return v;
}

__global__ __launch_bounds__(256) void mlp_k(const float4* __restrict__ agg4,
                                             const float* __restrict__ W1,
                                             const float* __restrict__ W2,
                                             float4* __restrict__ out4,
                                             int n_nodes, int do_norm) {
    __shared__ float4 sW1[DIM * WPAD];    // [j][k4], stride-17 pad
    __shared__ float4 sW2T[DIM * WPAD];   // [j][j2_4] = W2[j2][j] transposed, padded
    for (int i = threadIdx.x; i < DIM * (DIM / 4); i += blockDim.x) {
        int j = i >> 4, k4 = i & 15;
        sW1[j * WPAD + k4] = reinterpret_cast<const float4*>(W1)[i];
    }
    for (int i = threadIdx.x; i < DIM * DIM; i += blockDim.x) {
        int j2 = i >> 6, j = i & 63;   // W2[j2][j]
        reinterpret_cast<float*>(sW2T)[(j * WPAD + (j2 >> 2)) * 4 + (j2 & 3)] = W2[i];
    }
    __syncthreads();

    int t = blockIdx.x * blockDim.x + threadIdx.x;
    int node = t >> 2;
    int q = t & 3;
    if (node >= n_nodes) return;

    float4 a[DIM / 4];
#pragma unroll
    for (int k4 = 0; k4 < DIM / 4; ++k4)
        a[k4] = agg4[(size_t)node * 16 + k4];

    float4 o[DIM / 4];
#pragma unroll
    for (int j4 = 0; j4 < DIM / 4; ++j4) o[j4] = make_float4(0.f, 0.f, 0.f, 0.f);

#pragma unroll 2
    for (int jj = 0; jj < 16; ++jj) {
        int j = q + (jj << 2);          // stride-4 interleave across the quad
        float h0 = 0.f, h1 = 0.f, h2 = 0.f, h3 = 0.f;   // 4 parallel partials
#pragma unroll
        for (int k4 = 0; k4 < 16; k4 += 4) {
            float4 w0 = sW1[j * WPAD + k4];
            float4 w1 = sW1[j * WPAD + k4 + 1];
            float4 w2 = sW1[j * WPAD + k4 + 2];
            float4 w3 = sW1[j * WPAD + k4 + 3];
            h0 = fmaf(a[k4].x, w0.x, h0);     h0 = fmaf(a[k4].y, w0.y, h0);
            h0 = fmaf(a[k4].z, w0.z, h0);     h0 = fmaf(a[k4].w, w0.w, h0);
            h1 = fmaf(a[k4 + 1].x, w1.x, h1); h1 = fmaf(a[k4 + 1].y, w1.y, h1);
            h1 = fmaf(a[k4 + 1].z, w1.z, h1); h1 = fmaf(a[k4 + 1].w, w1.w, h1);
            h2 = fmaf(a[k4 + 2].x, w2.x, h2); h2 = fmaf(a[k4 + 2].y, w2.y, h2);
            h2 = fmaf(a[k4 + 2].z, w2.z, h2); h2 = fmaf(a[k4 + 2].w, w2.w, h2);
            h3 = fmaf(a[k4 + 3].x, w3.x, h3); h3 = fmaf(a[k4 + 3].y, w3.y, h3);
            h3 = fmaf(a[k4 + 3].z, w3.z, h3); h3 = fmaf(a[k4 + 3].w, w3.w, h3);
        }
        float h = fmaxf((h0 + h1) + (h2 + h3), 0.f);
#pragma unroll
        for (int j4 = 0; j4 < 16; ++j4) {
            float4 wv = sW2T[j * WPAD + j4];
            o[j4].x = fmaf(h, wv.x, o[j4].x);
            o[j4].y = fmaf(h, wv.y, o[j4].y);
            o[j4].z = fmaf(h, wv.z, o[j4].z);
            o[j4].w = fmaf(h, wv.w, o[j4].w);
        }
    }

#pragma unroll
    for (int j4 = 0; j4 < 16; ++j4) {
        float4 p = shfl_xor4(o[j4], 1);
        o[j4].x += p.x; o[j4].y += p.y; o[j4].z += p.z; o[j4].w += p.w;
        p = shfl_xor4(o[j4], 2);
        o[j4].x += p.x; o[j4].y += p.y; o[j4].z += p.z; o[j4].w += p.w;
    }

    if (q != 0) return;   // lane 0 of quad holds the full row now

    float scale = 1.f;
    if (do_norm) {
        float ss = 0.f;
#pragma unroll
        for (int j4 = 0; j4 < 16; ++j4) {
            ss = fmaf(o[j4].x, o[j4].x, ss);
            ss = fmaf(o[j4].y, o[j4].y, ss);
            ss = fmaf(o[j4].z, o[j4].z, ss);
            ss = fmaf(o[j4].w, o[j4].w, ss);
        }
        scale = 1.f / fmaxf(sqrtf(ss), 1e-12f);
    }

#pragma unroll
    for (int j4 = 0; j4 < 16; ++j4) {
        float4 v = o[j4];
        v.x *= scale; v.y *= scale; v.z *= scale; v.w *= scale;
        out4[(size_t)node * 16 + j4] = v;
    }
}

extern "C" void kernel_launch(void* const* d_in, const int* in_sizes, int n_in,
                              void* d_out, int out_size, void* d_ws, size_t ws_size,
                              hipStream_t stream) {
    const float* x    = (const float*)d_in[0];
    const int*   ei   = (const int*)d_in[1];     // [2,E]: src row then dst row
    const float* ew   = (const float*)d_in[2];
    const float* W1_0 = (const float*)d_in[3];
    const float* W2_0 = (const float*)d_in[4];
    const float* W1_1 = (const float*)d_in[5];
    const float* W2_1 = (const float*)d_in[6];
    float* out = (float*)d_out;

    int n_nodes = in_sizes[0] / DIM;
    int n_edges = in_sizes[2];

    char* p = (char*)d_ws;
    auto carve = [&](size_t bytes) {
        char* r = p;
        p += (bytes + 15) & ~(size_t)15;
        return r;
    };
    int nb = (n_nodes + SB - 1) / SB;                // 196 scan blocks (<=256)
    int*      cnt    = (int*)carve((size_t)n_nodes * sizeof(int));
    int*      offs   = (int*)carve(((size_t)n_nodes + 1) * sizeof(int));
    int*      cursor = (int*)carve((size_t)n_nodes * sizeof(int));
    int*      bsum   = (int*)carve((size_t)nb * sizeof(int));
    unsigned* se     = (unsigned*)carve((size_t)n_edges * sizeof(unsigned));  // 3.2MB
    float*    agg    = (float*)carve((size_t)n_nodes * DIM * sizeof(float));

    int eb  = (n_edges + 255) / 256;
    int gb  = (n_nodes * 16 + 255) / 256;    // 16 lanes per node (gather)
    int mb4 = (n_nodes * 4 + 255) / 256;     // 4 threads per node (mlp)

    // ---- build dst-CSR (shared by both layers) ----
    hipMemsetAsync(cnt, 0, (size_t)n_nodes * sizeof(int), stream);
    hist_k<<<eb, 256, 0, stream>>>(ei, cnt, n_edges);
    scan1_k<<<nb, SB, 0, stream>>>(cnt, bsum, n_nodes);
    scan3_k<<<nb, SB, 0, stream>>>(cnt, bsum, offs, cursor, n_nodes, nb);
    reorder_k<<<eb, 256, 0, stream>>>(ei, ew, cursor, se, n_edges);

    // ---- layer 1 ----
    gather_k<<<gb, 256, 0, stream>>>((const float4*)x, se, offs,
                                     (float4*)agg, n_nodes);
    mlp_k<<<mb4, 256, 0, stream>>>((const float4*)agg, W1_0, W2_0,
                                   (float4*)out, n_nodes, 0);

    // ---- layer 2 (x1 lives in d_out) ----
    gather_k<<<gb, 256, 0, stream>>>((const float4*)out, se, offs,
                                     (float4*)agg, n_nodes);
    mlp_k<<<mb4, 256, 0, stream>>>((const float4*)agg, W1_1, W2_1,
                                   (float4*)out, n_nodes, 1);
}

// Round 14
// 237.789 us; speedup vs baseline: 3.0168x; 1.3714x over previous
//
#include <hip/hip_runtime.h>

// WeightedGIN 2-layer + L2-normalize. N=50000, E=800000, D=64.
// CSR build (hist + 2-stage scan + float2 reorder, R7-style) + f16 feature
// tables + 16-lane gather + MFMA MLP (16x16x32_f16, weights in registers,
// H bounced through 2KB wave-private LDS).

typedef _Float16 f16;
typedef _Float16 f16x4 __attribute__((ext_vector_type(4)));
typedef _Float16 f16x8 __attribute__((ext_vector_type(8)));
typedef float f32x4 __attribute__((ext_vector_type(4)));

#define DIM 64
#define SB 256
#define HPAD 68   // f16 row stride of H bounce buffer (136B: 8B-aligned, bank-spread)

// ---- convert f32 features -> f16 table ----
__global__ __launch_bounds__(256) void cvt_k(const float4* __restrict__ in,
                                             f16x4* __restrict__ outv, int n4) {
    int i = blockIdx.x * blockDim.x + threadIdx.x;
    if (i >= n4) return;
    float4 v = in[i];
    f16x4 h;
    h[0] = (f16)v.x; h[1] = (f16)v.y; h[2] = (f16)v.z; h[3] = (f16)v.w;
    outv[i] = h;
}

// ---- histogram of dst ----
__global__ __launch_bounds__(256) void hist_k(const int* __restrict__ ei,
                                              int* __restrict__ cnt, int n_edges) {
    int e = blockIdx.x * blockDim.x + threadIdx.x;
    if (e < n_edges) atomicAdd(&cnt[ei[n_edges + e]], 1);
}

// ---- scan stage 1: per-block sums ----
__global__ __launch_bounds__(SB) void scan1_k(const int* __restrict__ cnt,
                                              int* __restrict__ bsum, int n) {
    __shared__ int red[SB];
    int i = blockIdx.x * SB + threadIdx.x;
    red[threadIdx.x] = (i < n) ? cnt[i] : 0;
    __syncthreads();
    for (int off = SB / 2; off > 0; off >>= 1) {
        if (threadIdx.x < off) red[threadIdx.x] += red[threadIdx.x + off];
        __syncthreads();
    }
    if (threadIdx.x == 0) bsum[blockIdx.x] = red[0];
}

// ---- scan stage 2: rescan bsum + local scan -> offs, cursor ----
__global__ __launch_bounds__(SB) void scan3_k(const int* __restrict__ cnt,
                                              const int* __restrict__ bsum,
                                              int* __restrict__ offs,
                                              int* __restrict__ cursor, int n, int nb) {
    __shared__ int sb[SB];
    __shared__ int sc[SB];
    int t = threadIdx.x;
    int bv = (t < nb) ? bsum[t] : 0;
    sb[t] = bv;
    __syncthreads();
    for (int off = 1; off < SB; off <<= 1) {
        int u = (t >= off) ? sb[t - off] : 0;
        __syncthreads();
        sb[t] += u;
        __syncthreads();
    }
    int block_off = (blockIdx.x == 0) ? 0 : sb[blockIdx.x - 1];
    __syncthreads();
    int i = blockIdx.x * SB + t;
    int v = (i < n) ? cnt[i] : 0;
    sc[t] = v;
    __syncthreads();
    for (int off = 1; off < SB; off <<= 1) {
        int u = (t >= off) ? sc[t - off] : 0;
        __syncthreads();
        sc[t] += u;
        __syncthreads();
    }
    int excl = sc[t] - v + block_off;
    if (i < n) { offs[i] = excl; cursor[i] = excl; }
    if (i == n - 1) offs[n] = excl + v;
}

// ---- scatter edges into dst-sorted float2 payload (src_bits, w) ----
__global__ __launch_bounds__(256) void reorder_k(const int* __restrict__ ei,
                                                 const float* __restrict__ ew,
                                                 int* __restrict__ cursor,
                                                 float2* __restrict__ se, int n_edges) {
    int e = blockIdx.x * blockDim.x + threadIdx.x;
    if (e >= n_edges) return;
    int s = ei[e];
    int d = ei[n_edges + e];
    int pos = atomicAdd(&cursor[d], 1);
    se[pos] = make_float2(__int_as_float(s), ew[e]);
}

// ---- gather: 16 lanes/node, f16 rows (128B), f32 accumulate, f16 agg out ----
__global__ __launch_bounds__(256) void gather_k(const f16x4* __restrict__ xh,  // [N][16] chunks
                                                const float2* __restrict__ se,
                                                const int* __restrict__ offs,
                                                f16x4* __restrict__ aggh, int n_nodes) {
    int t = blockIdx.x * blockDim.x + threadIdx.x;
    int node = t >> 4;
    int li = t & 15;
    if (node >= n_nodes) return;
    int beg = offs[node], end = offs[node + 1];

    float4 a0 = make_float4(0.f, 0.f, 0.f, 0.f);
    float4 a1 = make_float4(0.f, 0.f, 0.f, 0.f);
    float4 a2 = make_float4(0.f, 0.f, 0.f, 0.f);
    float4 a3 = make_float4(0.f, 0.f, 0.f, 0.f);

    int e = beg;
    for (; e + 3 < end; e += 4) {
        float2 p0 = se[e], p1 = se[e + 1], p2 = se[e + 2], p3 = se[e + 3];
        f16x4 v0 = xh[(size_t)__float_as_int(p0.x) * 16 + li];
        f16x4 v1 = xh[(size_t)__float_as_int(p1.x) * 16 + li];
        f16x4 v2 = xh[(size_t)__float_as_int(p2.x) * 16 + li];
        f16x4 v3 = xh[(size_t)__float_as_int(p3.x) * 16 + li];
        a0.x = fmaf(p0.y, (float)v0[0], a0.x); a0.y = fmaf(p0.y, (float)v0[1], a0.y);
        a0.z = fmaf(p0.y, (float)v0[2], a0.z); a0.w = fmaf(p0.y, (float)v0[3], a0.w);
        a1.x = fmaf(p1.y, (float)v1[0], a1.x); a1.y = fmaf(p1.y, (float)v1[1], a1.y);
        a1.z = fmaf(p1.y, (float)v1[2], a1.z); a1.w = fmaf(p1.y, (float)v1[3], a1.w);
        a2.x = fmaf(p2.y, (float)v2[0], a2.x); a2.y = fmaf(p2.y, (float)v2[1], a2.y);
        a2.z = fmaf(p2.y, (float)v2[2], a2.z); a2.w = fmaf(p2.y, (float)v2[3], a2.w);
        a3.x = fmaf(p3.y, (float)v3[0], a3.x); a3.y = fmaf(p3.y, (float)v3[1], a3.y);
        a3.z = fmaf(p3.y, (float)v3[2], a3.z); a3.w = fmaf(p3.y, (float)v3[3], a3.w);
    }
    for (; e < end; ++e) {
        float2 p = se[e];
        f16x4 v = xh[(size_t)__float_as_int(p.x) * 16 + li];
        a0.x = fmaf(p.y, (float)v[0], a0.x); a0.y = fmaf(p.y, (float)v[1], a0.y);
        a0.z = fmaf(p.y, (float)v[2], a0.z); a0.w = fmaf(p.y, (float)v[3], a0.w);
    }
    float rx = (a0.x + a1.x) + (a2.x + a3.x);
    float ry = (a0.y + a1.y) + (a2.y + a3.y);
    float rz = (a0.z + a1.z) + (a2.z + a3.z);
    float rw = (a0.w + a1.w) + (a2.w + a3.w);
    f16x4 o;
    o[0] = (f16)rx; o[1] = (f16)ry; o[2] = (f16)rz; o[3] = (f16)rw;
    aggh[(size_t)node * 16 + li] = o;
}

// ---- MFMA MLP: O = relu(A @ W1^T) @ W2^T ; A = agg f16 [N][64] ----
// Tile = 16 nodes/wave-iter. B-frags (weights) in registers, loaded once.
// k-slot map (consistent for A and B => exact): k = s*32 + g*4 + (i&3) + 16*(i>>2).
// C layout (verified m89): col=lane&15, row=(lane>>4)*4+reg.
__global__ __launch_bounds__(256) void mlp_mfma_k(const f16* __restrict__ agg,
                                                  const float* __restrict__ W1,
                                                  const float* __restrict__ W2,
                                                  f16* __restrict__ out_h,   // !do_norm
                                                  float* __restrict__ out_f, // do_norm
                                                  int n_tiles, int do_norm) {
    __shared__ f16 hbuf[4][16 * HPAD];
    int widx = threadIdx.x >> 6;
    int lane = threadIdx.x & 63;
    int col = lane & 15;
    int g = lane >> 4;
    int nwaves = gridDim.x * 4;
    int wgid = blockIdx.x * 4 + widx;

    // ---- load weight B-fragments (once per wave) ----
    f16x8 w1f[4][2], w2f[4][2];
#pragma unroll
    for (int t = 0; t < 4; ++t)
#pragma unroll
        for (int s = 0; s < 2; ++s) {
            f16x8 f1, f2;
#pragma unroll
            for (int i = 0; i < 8; ++i) {
                int k = s * 32 + g * 4 + (i & 3) + ((i >> 2) << 4);
                int n = t * 16 + col;
                f1[i] = (f16)W1[n * 64 + k];
                f2[i] = (f16)W2[n * 64 + k];
            }
            w1f[t][s] = f1;
            w2f[t][s] = f2;
        }

    f16* hb = &hbuf[widx][0];

    for (int tile = wgid; tile < n_tiles; tile += nwaves) {
        const f16* arow = agg + (size_t)tile * 16 * 64;
        // A-frags: row = col (node within tile), k per slot map
        f16x8 af[2];
#pragma unroll
        for (int s = 0; s < 2; ++s) {
            const f16* base = arow + col * 64 + s * 32 + g * 4;
            f16x4 lo = *reinterpret_cast<const f16x4*>(base);
            f16x4 hi = *reinterpret_cast<const f16x4*>(base + 16);
            f16x8 a;
#pragma unroll
            for (int i = 0; i < 4; ++i) { a[i] = lo[i]; a[i + 4] = hi[i]; }
            af[s] = a;
        }
        // GEMM1
        f32x4 hc[4];
#pragma unroll
        for (int t = 0; t < 4; ++t) hc[t] = (f32x4){0.f, 0.f, 0.f, 0.f};
#pragma unroll
        for (int s = 0; s < 2; ++s)
#pragma unroll
            for (int t = 0; t < 4; ++t)
                hc[t] = __builtin_amdgcn_mfma_f32_16x16x32_f16(af[s], w1f[t][s], hc[t], 0, 0, 0);
        // relu -> f16 -> LDS bounce (wave-private)
#pragma unroll
        for (int t = 0; t < 4; ++t)
#pragma unroll
            for (int r = 0; r < 4; ++r)
                hb[(g * 4 + r) * HPAD + t * 16 + col] = (f16)fmaxf(hc[t][r], 0.f);
        // A2-frags from LDS H
        f16x8 a2f[2];
#pragma unroll
        for (int s = 0; s < 2; ++s) {
            const f16* base = hb + col * HPAD + s * 32 + g * 4;
            f16x4 lo = *reinterpret_cast<const f16x4*>(base);
            f16x4 hi = *reinterpret_cast<const f16x4*>(base + 16);
            f16x8 a;
#pragma unroll
            for (int i = 0; i < 4; ++i) { a[i] = lo[i]; a[i + 4] = hi[i]; }
            a2f[s] = a;
        }
        // GEMM2
        f32x4 oc[4];
#pragma unroll
        for (int t = 0; t < 4; ++t) oc[t] = (f32x4){0.f, 0.f, 0.f, 0.f};
#pragma unroll
        for (int s = 0; s < 2; ++s)
#pragma unroll
            for (int t = 0; t < 4; ++t)
                oc[t] = __builtin_amdgcn_mfma_f32_16x16x32_f16(a2f[s], w2f[t][s], oc[t], 0, 0, 0);

        size_t rowbase = (size_t)tile * 16;
        if (!do_norm) {
#pragma unroll
            for (int t = 0; t < 4; ++t)
#pragma unroll
                for (int r = 0; r < 4; ++r)
                    out_h[(rowbase + g * 4 + r) * 64 + t * 16 + col] = (f16)oc[t][r];
        } else {
            float ss[4];
#pragma unroll
            for (int r = 0; r < 4; ++r) {
                float s2 = 0.f;
#pragma unroll
                for (int t = 0; t < 4; ++t) s2 = fmaf(oc[t][r], oc[t][r], s2);
                s2 += __shfl_xor(s2, 1, 64);
                s2 += __shfl_xor(s2, 2, 64);
                s2 += __shfl_xor(s2, 4, 64);
                s2 += __shfl_xor(s2, 8, 64);
                ss[r] = s2;
            }
#pragma unroll
            for (int r = 0; r < 4; ++r) {
                float sc = 1.f / fmaxf(sqrtf(ss[r]), 1e-12f);
#pragma unroll
                for (int t = 0; t < 4; ++t)
                    out_f[(rowbase + g * 4 + r) * 64 + t * 16 + col] = oc[t][r] * sc;
            }
        }
    }
}

extern "C" void kernel_launch(void* const* d_in, const int* in_sizes, int n_in,
                              void* d_out, int out_size, void* d_ws, size_t ws_size,
                              hipStream_t stream) {
    const float* x    = (const float*)d_in[0];
    const int*   ei   = (const int*)d_in[1];     // [2,E]: src row then dst row
    const float* ew   = (const float*)d_in[2];
    const float* W1_0 = (const float*)d_in[3];
    const float* W2_0 = (const float*)d_in[4];
    const float* W1_1 = (const float*)d_in[5];
    const float* W2_1 = (const float*)d_in[6];
    float* out = (float*)d_out;

    int n_nodes = in_sizes[0] / DIM;
    int n_edges = in_sizes[2];
    int n_tiles = (n_nodes + 15) / 16;   // 3125, exact for N=50000

    char* p = (char*)d_ws;
    auto carve = [&](size_t bytes) {
        char* r = p;
        p += (bytes + 15) & ~(size_t)15;
        return r;
    };
    int nb = (n_nodes + SB - 1) / SB;
    int*    cnt    = (int*)carve((size_t)n_nodes * sizeof(int));
    int*    offs   = (int*)carve(((size_t)n_nodes + 1) * sizeof(int));
    int*    cursor = (int*)carve((size_t)n_nodes * sizeof(int));
    int*    bsum   = (int*)carve((size_t)nb * sizeof(int));
    float2* se     = (float2*)carve((size_t)n_edges * sizeof(float2));        // 6.4MB
    f16*    xh     = (f16*)carve((size_t)n_nodes * DIM * sizeof(f16));        // 6.4MB
    f16*    aggh   = (f16*)carve((size_t)n_nodes * DIM * sizeof(f16));        // 6.4MB

    int eb  = (n_edges + 255) / 256;
    int gb  = (n_nodes * 16 + 255) / 256;        // gather: 16 lanes/node
    int cb  = (n_nodes * 16 + 255) / 256;        // cvt: N*16 float4 chunks
    int mfb = 256;                               // mlp: 256 blocks x 4 waves

    // ---- CSR build + f16 x table ----
    hipMemsetAsync(cnt, 0, (size_t)n_nodes * sizeof(int), stream);
    cvt_k<<<cb, 256, 0, stream>>>((const float4*)x, (f16x4*)xh, n_nodes * 16);
    hist_k<<<eb, 256, 0, stream>>>(ei, cnt, n_edges);
    scan1_k<<<nb, SB, 0, stream>>>(cnt, bsum, n_nodes);
    scan3_k<<<nb, SB, 0, stream>>>(cnt, bsum, offs, cursor, n_nodes, nb);
    reorder_k<<<eb, 256, 0, stream>>>(ei, ew, cursor, se, n_edges);

    // ---- layer 1 ----
    gather_k<<<gb, 256, 0, stream>>>((const f16x4*)xh, se, offs, (f16x4*)aggh, n_nodes);
    mlp_mfma_k<<<mfb, 256, 0, stream>>>(aggh, W1_0, W2_0, xh, nullptr, n_tiles, 0);

    // ---- layer 2 (x1 table reuses xh) ----
    gather_k<<<gb, 256, 0, stream>>>((const f16x4*)xh, se, offs, (f16x4*)aggh, n_nodes);
    mlp_mfma_k<<<mfb, 256, 0, stream>>>(aggh, W1_1, W2_1, nullptr, out, n_tiles, 1);
}